// Round 1
// baseline (663.407 us; speedup 1.0000x reference)
//
#include <hip/hip_runtime.h>
#include <math.h>

typedef _Float16 f16;
typedef _Float16 f16x8 __attribute__((ext_vector_type(8)));
typedef _Float16 f16x4 __attribute__((ext_vector_type(4)));
typedef float f32x4 __attribute__((ext_vector_type(4)));

#define DEVI static __device__ __forceinline__

constexpr int NB = 64, NN = 512, DSEM = 1024, DSPA = 1024, DFUSE = 512, ODIM = 4096;
constexpr int BM = 128, BN = 128, BK = 32, LDP = 40, NTHR = 256;

// ---------------- shared MFMA inner step: one BK=32 slice, 2x2 waves, 64x64/wave
DEVI void mma_tile(const f16* sa, const f16* sb, f32x4 (&acc)[4][4], int lane, int wm, int wn) {
  const int r = lane & 15, k8 = (lane >> 4) * 8;
  f16x8 af[4], bf[4];
#pragma unroll
  for (int i = 0; i < 4; ++i)
    af[i] = *(const f16x8*)(sa + (wm * 64 + i * 16 + r) * LDP + k8);
#pragma unroll
  for (int j = 0; j < 4; ++j)
    bf[j] = *(const f16x8*)(sb + (wn * 64 + j * 16 + r) * LDP + k8);
#pragma unroll
  for (int i = 0; i < 4; ++i)
#pragma unroll
    for (int j = 0; j < 4; ++j)
      acc[i][j] = __builtin_amdgcn_mfma_f32_16x16x32_f16(af[i], bf[j], acc[i][j], 0, 0, 0);
}

// ---------------- projection: P = relu(X @ W^T + b), f16 out --------------
__global__ __launch_bounds__(NTHR)
void proj_kernel(const float* __restrict__ X, const float* __restrict__ W,
                 const float* __restrict__ bias, f16* __restrict__ P, int K) {
  __shared__ f16 sa[BM * LDP];
  __shared__ f16 sb[BN * LDP];
  const int t = threadIdx.x, wave = t >> 6, lane = t & 63;
  const int wm = wave >> 1, wn = wave & 1;
  const int m0 = blockIdx.y * BM, f0 = blockIdx.x * BN;
  const int r2 = t >> 1, kv0 = (t & 1) * 4;
  f32x4 acc[4][4] = {};
  for (int k0 = 0; k0 < K; k0 += BK) {
#pragma unroll
    for (int i = 0; i < 4; ++i) {
      f32x4 v = *(const f32x4*)(X + (size_t)(m0 + r2) * K + k0 + (kv0 + i) * 4);
      f16x4 h = {(f16)v[0], (f16)v[1], (f16)v[2], (f16)v[3]};
      *(f16x4*)(sa + r2 * LDP + (kv0 + i) * 4) = h;
    }
#pragma unroll
    for (int i = 0; i < 4; ++i) {
      f32x4 v = *(const f32x4*)(W + (size_t)(f0 + r2) * K + k0 + (kv0 + i) * 4);
      f16x4 h = {(f16)v[0], (f16)v[1], (f16)v[2], (f16)v[3]};
      *(f16x4*)(sb + r2 * LDP + (kv0 + i) * 4) = h;
    }
    __syncthreads();
    mma_tile(sa, sb, acc, lane, wm, wn);
    __syncthreads();
  }
  const int lr = lane & 15, lq = lane >> 4;
  float bv[4];
#pragma unroll
  for (int j = 0; j < 4; ++j) bv[j] = bias[f0 + wn * 64 + j * 16 + lr];
#pragma unroll
  for (int i = 0; i < 4; ++i)
#pragma unroll
    for (int q = 0; q < 4; ++q) {
      const int row = m0 + wm * 64 + i * 16 + lq * 4 + q;
#pragma unroll
      for (int j = 0; j < 4; ++j) {
        float v = fmaxf(acc[i][j][q] + bv[j], 0.f);
        P[(size_t)row * DFUSE + f0 + wn * 64 + j * 16 + lr] = (f16)v;
      }
    }
}

// ---------------- sim = sem_p @ spa_p^T (per batch), fp32 out -------------
__global__ __launch_bounds__(NTHR)
void sim_kernel(const f16* __restrict__ P1, const f16* __restrict__ P2, float* __restrict__ sim) {
  __shared__ f16 sa[BM * LDP];
  __shared__ f16 sb[BN * LDP];
  const int t = threadIdx.x, wave = t >> 6, lane = t & 63;
  const int wm = wave >> 1, wn = wave & 1;
  const int b = blockIdx.z, n0 = blockIdx.y * BM, m0 = blockIdx.x * BN;
  const f16* A = P1 + (size_t)b * NN * DFUSE;
  const f16* Bm = P2 + (size_t)b * NN * DFUSE;
  float* S = sim + (size_t)b * NN * NN;
  const int r2 = t >> 1, h = t & 1;
  f32x4 acc[4][4] = {};
  for (int k0 = 0; k0 < DFUSE; k0 += BK) {
#pragma unroll
    for (int i = 0; i < 2; ++i) {
      f16x8 v = *(const f16x8*)(A + (size_t)(n0 + r2) * DFUSE + k0 + h * 16 + i * 8);
      *(f16x8*)(sa + r2 * LDP + h * 16 + i * 8) = v;
      f16x8 w = *(const f16x8*)(Bm + (size_t)(m0 + r2) * DFUSE + k0 + h * 16 + i * 8);
      *(f16x8*)(sb + r2 * LDP + h * 16 + i * 8) = w;
    }
    __syncthreads();
    mma_tile(sa, sb, acc, lane, wm, wn);
    __syncthreads();
  }
  const int lr = lane & 15, lq = lane >> 4;
#pragma unroll
  for (int i = 0; i < 4; ++i)
#pragma unroll
    for (int q = 0; q < 4; ++q)
#pragma unroll
      for (int j = 0; j < 4; ++j)
        S[(size_t)(n0 + wm * 64 + i * 16 + lq * 4 + q) * NN + m0 + wn * 64 + j * 16 + lr] =
            acc[i][j][q];
}

// ---------------- row softmax stats (over m, masked m<count) --------------
__global__ __launch_bounds__(256)
void row_stats_kernel(const float* __restrict__ sim, const int* __restrict__ counts,
                      float* __restrict__ rowmax, float* __restrict__ rrowsum) {
  const int wave = threadIdx.x >> 6, lane = threadIdx.x & 63;
  const int row = blockIdx.x * 4 + wave;       // [0, NB*NN)
  const int count = counts[row >> 9];
  const float* sr = sim + (size_t)row * NN;
  float v[8], mx = -INFINITY;
#pragma unroll
  for (int i = 0; i < 8; ++i) {
    const int m = lane + 64 * i;
    v[i] = sr[m];
    if (m < count) mx = fmaxf(mx, v[i]);
  }
#pragma unroll
  for (int off = 32; off; off >>= 1) mx = fmaxf(mx, __shfl_xor(mx, off, 64));
  float s = 0.f;
#pragma unroll
  for (int i = 0; i < 8; ++i) {
    const int m = lane + 64 * i;
    if (m < count) s += __expf(v[i] - mx);
  }
#pragma unroll
  for (int off = 32; off; off >>= 1) s += __shfl_xor(s, off, 64);
  if (lane == 0) { rowmax[row] = mx; rrowsum[row] = 1.f / s; }
}

// ---------------- column softmax stats (over n<count), 2-stage -----------
__global__ __launch_bounds__(512)
void col_partial_kernel(const float* __restrict__ sim, const int* __restrict__ counts,
                        float* __restrict__ pmax, float* __restrict__ psum) {
  const int b = blockIdx.x, q = blockIdx.y, m = threadIdx.x;
  const int count = counts[b];
  const float* S = sim + (size_t)b * NN * NN;
  const int nbeg = q * 128, nend = min(nbeg + 128, count);
  float mx = -INFINITY;
  for (int n = nbeg; n < nend; ++n) mx = fmaxf(mx, S[(size_t)n * NN + m]);
  float s = 0.f;
  for (int n = nbeg; n < nend; ++n) s += __expf(S[(size_t)n * NN + m] - mx);
  pmax[(size_t)(b * 4 + q) * NN + m] = mx;
  psum[(size_t)(b * 4 + q) * NN + m] = s;
}

__global__ __launch_bounds__(512)
void col_merge_kernel(const float* __restrict__ pmax, const float* __restrict__ psum,
                      float* __restrict__ colmax, float* __restrict__ rcolsum) {
  const int b = blockIdx.x, m = threadIdx.x;
  float mx = -INFINITY;
#pragma unroll
  for (int q = 0; q < 4; ++q) mx = fmaxf(mx, pmax[(size_t)(b * 4 + q) * NN + m]);
  float s = 0.f;
#pragma unroll
  for (int q = 0; q < 4; ++q)
    s += psum[(size_t)(b * 4 + q) * NN + m] * __expf(pmax[(size_t)(b * 4 + q) * NN + m] - mx);
  colmax[(size_t)b * NN + m] = mx;
  rcolsum[(size_t)b * NN + m] = 1.f / s;
}

// ------- apply1: out[:,n,1024:2048] = softmax_m(sim) @ spatial_x ----------
__global__ __launch_bounds__(NTHR)
void apply1_kernel(const float* __restrict__ sim, const float* __restrict__ rowmax,
                   const float* __restrict__ rrowsum, const float* __restrict__ spax,
                   const int* __restrict__ counts, float* __restrict__ out) {
  __shared__ f16 sa[BM * LDP];
  __shared__ f16 sb[BN * LDP];
  const int t = threadIdx.x, wave = t >> 6, lane = t & 63;
  const int wm = wave >> 1, wn = wave & 1;
  const int b = blockIdx.z, n0 = blockIdx.y * BM, d0 = blockIdx.x * BN;
  const int count = counts[b];
  const float* S = sim + (size_t)b * NN * NN;
  const float* Xs = spax + (size_t)b * NN * DSPA;
  const int r2 = t >> 1, kv0 = (t & 1) * 4;
  const float rm = rowmax[(size_t)b * NN + n0 + r2];
  const float rs = rrowsum[(size_t)b * NN + n0 + r2];
  const int kb = t >> 3, dv = t & 7;
  const int Kend = min(NN, ((count + BK - 1) / BK) * BK);
  f32x4 acc[4][4] = {};
  for (int k0 = 0; k0 < Kend; k0 += BK) {
#pragma unroll
    for (int i = 0; i < 4; ++i) {   // A: att[n][m] on the fly (k-contig, no transpose)
      f32x4 v = *(const f32x4*)(S + (size_t)(n0 + r2) * NN + k0 + (kv0 + i) * 4);
      f16x4 hh;
#pragma unroll
      for (int c = 0; c < 4; ++c) {
        const int m = k0 + (kv0 + i) * 4 + c;
        hh[c] = (f16)((m < count) ? __expf(v[c] - rm) * rs : 0.f);
      }
      *(f16x4*)(sa + r2 * LDP + (kv0 + i) * 4) = hh;
    }
#pragma unroll
    for (int i = 0; i < 4; ++i) {   // B: spatial_x[k=m][d] transposed into [d][k]
      const int dd = (dv + 8 * i) * 4;
      f32x4 v = *(const f32x4*)(Xs + (size_t)(k0 + kb) * DSPA + d0 + dd);
#pragma unroll
      for (int c = 0; c < 4; ++c) sb[(dd + c) * LDP + kb] = (f16)v[c];
    }
    __syncthreads();
    mma_tile(sa, sb, acc, lane, wm, wn);
    __syncthreads();
  }
  const int lr = lane & 15, lq = lane >> 4;
  float* O = out + (size_t)b * NN * ODIM + 1024;
#pragma unroll
  for (int i = 0; i < 4; ++i)
#pragma unroll
    for (int q = 0; q < 4; ++q) {
      const int row = n0 + wm * 64 + i * 16 + lq * 4 + q;
      const bool valid = row < count;
#pragma unroll
      for (int j = 0; j < 4; ++j)
        O[(size_t)row * ODIM + d0 + wn * 64 + j * 16 + lr] = valid ? acc[i][j][q] : 0.f;
    }
}

// ------- apply2: out[:,m,3072:4096] = softmax_n(sim)^T @ semantic_x -------
__global__ __launch_bounds__(NTHR)
void apply2_kernel(const float* __restrict__ sim, const float* __restrict__ colmax,
                   const float* __restrict__ rcolsum, const float* __restrict__ semx,
                   const int* __restrict__ counts, float* __restrict__ out) {
  __shared__ f16 sa[BM * LDP];
  __shared__ f16 sb[BN * LDP];
  __shared__ float cmx[BM];
  __shared__ float crs[BM];
  const int t = threadIdx.x, wave = t >> 6, lane = t & 63;
  const int wm = wave >> 1, wn = wave & 1;
  const int b = blockIdx.z, m0 = blockIdx.y * BM, d0 = blockIdx.x * BN;
  const int count = counts[b];
  const float* S = sim + (size_t)b * NN * NN;
  const float* Xm = semx + (size_t)b * NN * DSEM;
  if (t < BM) {
    cmx[t] = colmax[(size_t)b * NN + m0 + t];
    crs[t] = rcolsum[(size_t)b * NN + m0 + t];
  }
  __syncthreads();
  const int kb = t >> 3, dv = t & 7;
  const int Kend = min(NN, ((count + BK - 1) / BK) * BK);
  f32x4 acc[4][4] = {};
  for (int k0 = 0; k0 < Kend; k0 += BK) {
    const bool kvalid = (k0 + kb) < count;
#pragma unroll
    for (int i = 0; i < 4; ++i) {
      const int dd = (dv + 8 * i) * 4;
      // A: att_spa[n][m] -> sa[m][n] transposed, exp on the fly
      f32x4 v = *(const f32x4*)(S + (size_t)(k0 + kb) * NN + m0 + dd);
#pragma unroll
      for (int c = 0; c < 4; ++c)
        sa[(dd + c) * LDP + kb] = (f16)(kvalid ? __expf(v[c] - cmx[dd + c]) * crs[dd + c] : 0.f);
      // B: semantic_x[k=n][d] transposed into [d][k]
      f32x4 w = *(const f32x4*)(Xm + (size_t)(k0 + kb) * DSEM + d0 + dd);
#pragma unroll
      for (int c = 0; c < 4; ++c) sb[(dd + c) * LDP + kb] = (f16)w[c];
    }
    __syncthreads();
    mma_tile(sa, sb, acc, lane, wm, wn);
    __syncthreads();
  }
  const int lr = lane & 15, lq = lane >> 4;
  float* O = out + (size_t)b * NN * ODIM + 3072;
#pragma unroll
  for (int i = 0; i < 4; ++i)
#pragma unroll
    for (int q = 0; q < 4; ++q) {
      const int row = m0 + wm * 64 + i * 16 + lq * 4 + q;
      const bool valid = row < count;
#pragma unroll
      for (int j = 0; j < 4; ++j)
        O[(size_t)row * ODIM + d0 + wn * 64 + j * 16 + lr] = valid ? acc[i][j][q] : 0.f;
    }
}

// ------- assemble: slots 0 (semantic_x) and 2 (spatial_x), masked ---------
__global__ __launch_bounds__(256)
void assemble_kernel(const float* __restrict__ semx, const float* __restrict__ spax,
                     const int* __restrict__ counts, float* __restrict__ out) {
  const size_t total = (size_t)NB * NN * (DSEM / 4);
  const size_t stride = (size_t)gridDim.x * blockDim.x;
  for (size_t idx = (size_t)blockIdx.x * blockDim.x + threadIdx.x; idx < total; idx += stride) {
    const int d4 = (int)(idx & 255);
    const int n = (int)((idx >> 8) & 511);
    const int b = (int)(idx >> 17);
    const float s = (n < counts[b]) ? 1.f : 0.f;
    f32x4 vs = *(const f32x4*)(semx + idx * 4);
    f32x4 vp = *(const f32x4*)(spax + idx * 4);
    vs *= s;
    vp *= s;
    float* o = out + ((size_t)b * NN + n) * ODIM;
    *(f32x4*)(o + d4 * 4) = vs;
    *(f32x4*)(o + 2048 + d4 * 4) = vp;
  }
}

extern "C" void kernel_launch(void* const* d_in, const int* in_sizes, int n_in,
                              void* d_out, int out_size, void* d_ws, size_t ws_size,
                              hipStream_t stream) {
  const float* semx = (const float*)d_in[0];
  const float* spax = (const float*)d_in[1];
  const float* Wsem = (const float*)d_in[2];
  const float* bsem = (const float*)d_in[3];
  const float* Wspa = (const float*)d_in[4];
  const float* bspa = (const float*)d_in[5];
  const int* counts = (const int*)d_in[6];
  float* out = (float*)d_out;
  char* ws = (char*)d_ws;

  f16* semp = (f16*)(ws);                          // 33,554,432 B
  f16* spap = (f16*)(ws + 33554432);               // 33,554,432 B
  float* sim = (float*)(ws + 67108864);            // 67,108,864 B
  float* rowmax = (float*)(ws + 134217728);        // 131,072 B
  float* rrowsum = (float*)(ws + 134348800);       // 131,072 B
  float* colmax = (float*)(ws + 134479872);        // 131,072 B
  float* rcolsum = (float*)(ws + 134610944);       // 131,072 B
  float* pmax = (float*)(ws + 134742016);          // 524,288 B
  float* psum = (float*)(ws + 135266304);          // 524,288 B -> total ~129.5 MB

  const dim3 blk(NTHR);
  proj_kernel<<<dim3(4, 256), blk, 0, stream>>>(semx, Wsem, bsem, semp, DSEM);
  proj_kernel<<<dim3(4, 256), blk, 0, stream>>>(spax, Wspa, bspa, spap, DSPA);
  sim_kernel<<<dim3(4, 4, NB), blk, 0, stream>>>(semp, spap, sim);
  row_stats_kernel<<<dim3(8192), dim3(256), 0, stream>>>(sim, counts, rowmax, rrowsum);
  col_partial_kernel<<<dim3(NB, 4), dim3(512), 0, stream>>>(sim, counts, pmax, psum);
  col_merge_kernel<<<dim3(NB), dim3(512), 0, stream>>>(pmax, psum, colmax, rcolsum);
  apply1_kernel<<<dim3(8, 4, NB), blk, 0, stream>>>(sim, rowmax, rrowsum, spax, counts, out);
  apply2_kernel<<<dim3(8, 4, NB), blk, 0, stream>>>(sim, colmax, rcolsum, semx, counts, out);
  assemble_kernel<<<dim3(2048), dim3(256), 0, stream>>>(semx, spax, counts, out);
}